// Round 13
// baseline (147.637 us; speedup 1.0000x reference)
//
#include <hip/hip_runtime.h>
#include <hip/hip_bf16.h>
#include <cstdint>

#define B_    8
#define C_    128
#define IC_   64
#define N_    2048
#define LOG2E 1.44269504088896340736f

typedef __attribute__((ext_vector_type(8))) short bf16x8;
typedef __attribute__((ext_vector_type(4))) float f32x4;

// workspace layout (float offsets)
#define OFF_FT    0          // B*N f32 (pre-scaled by log2e)
#define OFF_FP    16384      // B*N f32 (pre-scaled by log2e)
#define OFF_ADJP  32768      // uchar[2048][256] row bitmasks = 512 KB
#define OFF_GXB   163840     // bf16 B-fragments [B][64 jt][4 ot][64 lane][8] = 2 MB

static __device__ __forceinline__ ushort f2bf(float f) {
  __hip_bfloat16 h = __float2bfloat16(f);
  return *reinterpret_cast<ushort*>(&h);
}

// ---------------------------------------------------------------------------
// K0: pack adj (int32 [N][N]) -> row bitmasks (bit j of byte j>>3 = adj>0).
// one block per row i; thread t packs j = t*8 .. t*8+7.
// ---------------------------------------------------------------------------
__global__ __launch_bounds__(256) void k_pack(const int* __restrict__ adj,
                                              float* __restrict__ ws) {
  int i = blockIdx.x, t = threadIdx.x;
  const int4* ap = (const int4*)(adj + (size_t)i * N_) + t * 2;
  int4 a0 = ap[0], a1 = ap[1];
  unsigned m = 0;
  m |= (a0.x > 0) ? 1u   : 0u;  m |= (a0.y > 0) ? 2u   : 0u;
  m |= (a0.z > 0) ? 4u   : 0u;  m |= (a0.w > 0) ? 8u   : 0u;
  m |= (a1.x > 0) ? 16u  : 0u;  m |= (a1.y > 0) ? 32u  : 0u;
  m |= (a1.z > 0) ? 64u  : 0u;  m |= (a1.w > 0) ? 128u : 0u;
  ((unsigned char*)(ws + OFF_ADJP))[(size_t)i * 256 + t] = (unsigned char)m;
}

// ---------------------------------------------------------------------------
// K1: gx B-fragments + f_t/f_p.
// gxB[b][jt][ot][lane][k8] = bf16(sum_c g_w[o][c]*x[b][c][n] + g_b[o])
//   with o = ot*16 + (lane&15), n = jt*32 + (lane>>4)*8 + k8
// -> in k_attn, one coalesced 1KB load per (window, ot) IS the MFMA B-frag.
// ---------------------------------------------------------------------------
__global__ __launch_bounds__(256) void k_gx(const float* __restrict__ x,
                                            const float* __restrict__ g_w,
                                            const float* __restrict__ g_b,
                                            const float* __restrict__ theta_w,
                                            const float* __restrict__ theta_b,
                                            const float* __restrict__ phi_w,
                                            const float* __restrict__ phi_b,
                                            const float* __restrict__ cp_w,
                                            float* __restrict__ ws) {
  __shared__ float xs[C_][64];      // 32 KB
  __shared__ float wgT[C_][IC_];    // 32 KB
  __shared__ float vtp[2][C_];      // 1 KB
  __shared__ float fred[2][4][64];  // 2 KB
  __shared__ float fb[2];
  int bx = blockIdx.x;
  int b = bx >> 5, n0 = (bx & 31) * 64;
  int t = threadIdx.x;

  const float* xb = x + (size_t)b * C_ * N_ + n0;
  for (int idx = t; idx < C_ * 64; idx += 256) {
    int c = idx >> 6, n = idx & 63;
    xs[c][n] = xb[(size_t)c * N_ + n];
  }
  for (int idx = t; idx < C_ * IC_; idx += 256) {
    int c = idx >> 6, o = idx & 63;
    wgT[c][o] = g_w[o * C_ + c];
  }
  {
    int half = t >> 7, c = t & 127;
    const float* wmat = half ? phi_w : theta_w;
    const float* cw = cp_w + half * IC_;
    float a = 0.f;
#pragma unroll 8
    for (int o = 0; o < IC_; ++o) a += cw[o] * wmat[o * C_ + c];
    vtp[half][c] = a * LOG2E;
  }
  if (t < 2) {
    const float* bv = t ? phi_b : theta_b;
    const float* cw = cp_w + t * IC_;
    float a = 0.f;
    for (int o = 0; o < IC_; ++o) a += cw[o] * bv[o];
    fb[t] = a * LOG2E;
  }
  __syncthreads();

  int o4 = (t & 15) * 4, n4 = (t >> 4) * 4;
  float acc[4][4] = {};
#pragma unroll 4
  for (int c = 0; c < C_; ++c) {
    float4 xv = *(const float4*)&xs[c][n4];
    float4 wv = *(const float4*)&wgT[c][o4];
    acc[0][0] += wv.x * xv.x; acc[0][1] += wv.x * xv.y; acc[0][2] += wv.x * xv.z; acc[0][3] += wv.x * xv.w;
    acc[1][0] += wv.y * xv.x; acc[1][1] += wv.y * xv.y; acc[1][2] += wv.y * xv.z; acc[1][3] += wv.y * xv.w;
    acc[2][0] += wv.z * xv.x; acc[2][1] += wv.z * xv.y; acc[2][2] += wv.z * xv.z; acc[2][3] += wv.z * xv.w;
    acc[3][0] += wv.w * xv.x; acc[3][1] += wv.w * xv.y; acc[3][2] += wv.w * xv.z; acc[3][3] += wv.w * xv.w;
  }
  // store as B-fragments
  __hip_bfloat16* gxB = (__hip_bfloat16*)(ws + OFF_GXB);
  int n4g = n0 + n4;                    // 4 consecutive n share jt, lane-hi, half
  int jt  = n4g >> 5;
  int lhi = ((n4g >> 3) & 3) << 4;
  int sub = n4g & 7;                    // 0 or 4
#pragma unroll
  for (int oo = 0; oo < 4; ++oo) {
    int o = o4 + oo;
    float gb = g_b[o];
    ushort4 pk = make_ushort4(f2bf(acc[oo][0] + gb), f2bf(acc[oo][1] + gb),
                              f2bf(acc[oo][2] + gb), f2bf(acc[oo][3] + gb));
    size_t idx = ((((size_t)b * 64 + jt) * 4 + (o >> 4)) * 64 + ((o & 15) | lhi)) * 8 + sub;
    *(ushort4*)(gxB + idx) = pk;
  }

  // f tail
  {
    int n = t & 63, qr = t >> 6;
    float ft = 0.f, fp = 0.f;
#pragma unroll 8
    for (int cc = 0; cc < 32; ++cc) {
      int c = qr * 32 + cc;
      float xv = xs[c][n];
      ft += xv * vtp[0][c];
      fp += xv * vtp[1][c];
    }
    fred[0][qr][n] = ft;
    fred[1][qr][n] = fp;
  }
  __syncthreads();
  if (t < 128) {
    int n = t & 63, isp = t >> 6;
    float f = fb[isp] + fred[isp][0][n] + fred[isp][1][n]
            + fred[isp][2][n] + fred[isp][3][n];
    ws[(isp ? OFF_FP : OFF_FT) + b * N_ + n0 + n] = f;
  }
}

// ---------------------------------------------------------------------------
// K2: fused attention — zero-LDS/zero-barrier (r11 structure) with ALL loads
// de-gathered: B-frag = 1 coalesced 1KB gxB load; adj = 1 broadcast u32 of
// bitmask; f_p = 2 broadcast float4. Depth-2 prefetch in named slots.
// Wave: (w>>1) row-half of 32-row supertile, (w&1) o-half; P 2x redundant.
// ---------------------------------------------------------------------------
__global__ __launch_bounds__(256, 2) void k_attn(const float* __restrict__ ws,
                                                 float* __restrict__ out) {
  int bx = blockIdx.x;
  int b = bx >> 6, st = bx & 63;
  int t = threadIdx.x;
  int w = t >> 6, lane = t & 63;
  int col = lane & 15, agrp = lane >> 4;
  int rowbase = st * 32 + (w >> 1) * 16;
  int obase = (w & 1) * 32;
  int ot0 = (w & 1) * 2;

  const float* f_t = ws + OFF_FT + b * N_;
  const unsigned char* ap = (const unsigned char*)(ws + OFF_ADJP)
                          + (size_t)(rowbase + col) * 256;
  const float4* fpv = (const float4*)(ws + OFF_FP + b * N_);
  const bf16x8* gx = (const bf16x8*)(ws + OFF_GXB)
                   + (size_t)b * 64 * 4 * 64 + lane;

  float fti = f_t[rowbase + col];

  unsigned mA, mB; float4 f0A, f1A, f0B, f1B; bf16x8 g0A, g1A, g0B, g1B;
#define LOADW(ks_, m_, f0_, f1_, g0_, g1_)            \
  { int k_ = (ks_);                                   \
    m_  = *(const unsigned*)(ap + k_ * 4);            \
    f0_ = fpv[k_ * 8 + agrp * 2];                     \
    f1_ = fpv[k_ * 8 + agrp * 2 + 1];                 \
    g0_ = gx[(k_ * 4 + ot0) * 64];                    \
    g1_ = gx[(k_ * 4 + ot0 + 1) * 64]; }

  LOADW(0, mA, f0A, f1A, g0A, g1A);
  LOADW(1, mB, f0B, f1B, g0B, g1B);

  f32x4 acc0 = {0.f, 0.f, 0.f, 0.f};
  f32x4 acc1 = {0.f, 0.f, 0.f, 0.f};
  float rsum = 0.f;

#define BODY(m_, f0_, f1_, g0_, g1_)                                         \
  { unsigned mb = (m_ >> (agrp * 8)) & 0xffu;                                \
    float s0 = fti + f0_.x; s0 = fmaxf(s0, 0.2f * s0);                       \
    float s1 = fti + f0_.y; s1 = fmaxf(s1, 0.2f * s1);                       \
    float s2 = fti + f0_.z; s2 = fmaxf(s2, 0.2f * s2);                       \
    float s3 = fti + f0_.w; s3 = fmaxf(s3, 0.2f * s3);                       \
    float s4 = fti + f1_.x; s4 = fmaxf(s4, 0.2f * s4);                       \
    float s5 = fti + f1_.y; s5 = fmaxf(s5, 0.2f * s5);                       \
    float s6 = fti + f1_.z; s6 = fmaxf(s6, 0.2f * s6);                       \
    float s7 = fti + f1_.w; s7 = fmaxf(s7, 0.2f * s7);                       \
    float p0 = (mb & 1u)   ? 0.f : exp2f(s0);                                \
    float p1 = (mb & 2u)   ? 0.f : exp2f(s1);                                \
    float p2 = (mb & 4u)   ? 0.f : exp2f(s2);                                \
    float p3 = (mb & 8u)   ? 0.f : exp2f(s3);                                \
    float p4 = (mb & 16u)  ? 0.f : exp2f(s4);                                \
    float p5 = (mb & 32u)  ? 0.f : exp2f(s5);                                \
    float p6 = (mb & 64u)  ? 0.f : exp2f(s6);                                \
    float p7 = (mb & 128u) ? 0.f : exp2f(s7);                                \
    rsum += ((p0 + p1) + (p2 + p3)) + ((p4 + p5) + (p6 + p7));               \
    bf16x8 af;                                                               \
    af[0] = (short)f2bf(p0); af[1] = (short)f2bf(p1);                        \
    af[2] = (short)f2bf(p2); af[3] = (short)f2bf(p3);                        \
    af[4] = (short)f2bf(p4); af[5] = (short)f2bf(p5);                        \
    af[6] = (short)f2bf(p6); af[7] = (short)f2bf(p7);                        \
    acc0 = __builtin_amdgcn_mfma_f32_16x16x32_bf16(af, g0_, acc0, 0, 0, 0);  \
    acc1 = __builtin_amdgcn_mfma_f32_16x16x32_bf16(af, g1_, acc1, 0, 0, 0); }

  for (int ks = 0; ks < 64; ks += 2) {
    BODY(mA, f0A, f1A, g0A, g1A);
    { int nk = (ks + 2 < 64) ? ks + 2 : 62; LOADW(nk, mA, f0A, f1A, g0A, g1A); }
    BODY(mB, f0B, f1B, g0B, g1B);
    { int nk = (ks + 3 < 64) ? ks + 3 : 63; LOADW(nk, mB, f0B, f1B, g0B, g1B); }
  }

  // row sums: combine the 4 k-subgroups of each row
  rsum += __shfl_xor(rsum, 16, 64);
  rsum += __shfl_xor(rsum, 32, 64);
  float r0 = __shfl(rsum, agrp * 4 + 0, 64);
  float r1 = __shfl(rsum, agrp * 4 + 1, 64);
  float r2 = __shfl(rsum, agrp * 4 + 2, 64);
  float r3 = __shfl(rsum, agrp * 4 + 3, 64);

  float4 res0 = make_float4(acc0[0] / r0, acc0[1] / r1, acc0[2] / r2, acc0[3] / r3);
  float4 res1 = make_float4(acc1[0] / r0, acc1[1] / r1, acc1[2] / r2, acc1[3] / r3);
  float* op = out + ((size_t)b * IC_ + obase + col) * N_ + rowbase + agrp * 4;
  *(float4*)op             = res0;
  *(float4*)(op + 16 * N_) = res1;
#undef LOADW
#undef BODY
}

// ---------------------------------------------------------------------------
extern "C" void kernel_launch(void* const* d_in, const int* in_sizes, int n_in,
                              void* d_out, int out_size, void* d_ws, size_t ws_size,
                              hipStream_t stream) {
  const float* x       = (const float*)d_in[0];
  const int*   adj     = (const int*)  d_in[1];
  const float* g_w     = (const float*)d_in[2];
  const float* g_b     = (const float*)d_in[3];
  const float* theta_w = (const float*)d_in[4];
  const float* theta_b = (const float*)d_in[5];
  const float* phi_w   = (const float*)d_in[6];
  const float* phi_b   = (const float*)d_in[7];
  const float* cp_w    = (const float*)d_in[8];
  float* out = (float*)d_out;
  float* ws  = (float*)d_ws;

  k_pack<<<N_, 256, 0, stream>>>(adj, ws);
  k_gx<<<B_ * (N_ / 64), 256, 0, stream>>>(x, g_w, g_b, theta_w, theta_b,
                                           phi_w, phi_b, cp_w, ws);
  k_attn<<<B_ * (N_ / 32), 256, 0, stream>>>(ws, out);
}

// Round 14
// 123.137 us; speedup vs baseline: 1.1990x; 1.1990x over previous
//
#include <hip/hip_runtime.h>
#include <hip/hip_bf16.h>
#include <cstdint>

#define B_    8
#define C_    128
#define IC_   64
#define N_    2048
#define LOG2E 1.44269504088896340736f

typedef __attribute__((ext_vector_type(8))) short bf16x8;
typedef __attribute__((ext_vector_type(4))) float f32x4;

// workspace layout (float offsets)
#define OFF_FT    0          // B*N f32 (pre-scaled by log2e)
#define OFF_FP    16384      // B*N f32 (pre-scaled by log2e)
#define OFF_ADJP  32768      // u32 [64 jt][2048 row] window masks = 512 KB
#define OFF_GXB   163840     // bf16 B-fragments [B][64 jt][4 ot][64 lane][8] = 2 MB

static __device__ __forceinline__ ushort f2bf(float f) {
  __hip_bfloat16 h = __float2bfloat16(f);
  return *reinterpret_cast<ushort*>(&h);
}

// ---------------------------------------------------------------------------
// K0: pack adj -> transposed window masks adjP[jt][i]: bit (j&31) of
// adjP[j>>5][i] = (adj[i][j] > 0). One ballot per 64 j (wave-wide test).
// Block = row i, 4 waves; wave w covers j = w*512 .. +511.
// ---------------------------------------------------------------------------
__global__ __launch_bounds__(256) void k_pack(const int* __restrict__ adj,
                                              float* __restrict__ ws) {
  int i = blockIdx.x, t = threadIdx.x;
  int w = t >> 6, lane = t & 63;
  unsigned* adjP = (unsigned*)(ws + OFF_ADJP);
  const int* arow = adj + (size_t)i * N_ + w * 512;
#pragma unroll
  for (int k = 0; k < 8; ++k) {
    unsigned long long m = __ballot(arow[k * 64 + lane] > 0);
    if (lane == 0) {
      int jt = w * 16 + k * 2;
      adjP[(size_t)jt * 2048 + i]       = (unsigned)m;
      adjP[(size_t)(jt + 1) * 2048 + i] = (unsigned)(m >> 32);
    }
  }
}

// ---------------------------------------------------------------------------
// K1: gx B-fragments + f_t/f_p (unchanged from r13 — HW-verified layout).
// gxB[b][jt][ot][lane][k8], o = ot*16 + (lane&15), n = jt*32 + (lane>>4)*8 + k8
// ---------------------------------------------------------------------------
__global__ __launch_bounds__(256) void k_gx(const float* __restrict__ x,
                                            const float* __restrict__ g_w,
                                            const float* __restrict__ g_b,
                                            const float* __restrict__ theta_w,
                                            const float* __restrict__ theta_b,
                                            const float* __restrict__ phi_w,
                                            const float* __restrict__ phi_b,
                                            const float* __restrict__ cp_w,
                                            float* __restrict__ ws) {
  __shared__ float xs[C_][64];      // 32 KB
  __shared__ float wgT[C_][IC_];    // 32 KB
  __shared__ float vtp[2][C_];      // 1 KB
  __shared__ float fred[2][4][64];  // 2 KB
  __shared__ float fb[2];
  int bx = blockIdx.x;
  int b = bx >> 5, n0 = (bx & 31) * 64;
  int t = threadIdx.x;

  const float* xb = x + (size_t)b * C_ * N_ + n0;
  for (int idx = t; idx < C_ * 64; idx += 256) {
    int c = idx >> 6, n = idx & 63;
    xs[c][n] = xb[(size_t)c * N_ + n];
  }
  for (int idx = t; idx < C_ * IC_; idx += 256) {
    int c = idx >> 6, o = idx & 63;
    wgT[c][o] = g_w[o * C_ + c];
  }
  {
    int half = t >> 7, c = t & 127;
    const float* wmat = half ? phi_w : theta_w;
    const float* cw = cp_w + half * IC_;
    float a = 0.f;
#pragma unroll 8
    for (int o = 0; o < IC_; ++o) a += cw[o] * wmat[o * C_ + c];
    vtp[half][c] = a * LOG2E;
  }
  if (t < 2) {
    const float* bv = t ? phi_b : theta_b;
    const float* cw = cp_w + t * IC_;
    float a = 0.f;
    for (int o = 0; o < IC_; ++o) a += cw[o] * bv[o];
    fb[t] = a * LOG2E;
  }
  __syncthreads();

  int o4 = (t & 15) * 4, n4 = (t >> 4) * 4;
  float acc[4][4] = {};
#pragma unroll 4
  for (int c = 0; c < C_; ++c) {
    float4 xv = *(const float4*)&xs[c][n4];
    float4 wv = *(const float4*)&wgT[c][o4];
    acc[0][0] += wv.x * xv.x; acc[0][1] += wv.x * xv.y; acc[0][2] += wv.x * xv.z; acc[0][3] += wv.x * xv.w;
    acc[1][0] += wv.y * xv.x; acc[1][1] += wv.y * xv.y; acc[1][2] += wv.y * xv.z; acc[1][3] += wv.y * xv.w;
    acc[2][0] += wv.z * xv.x; acc[2][1] += wv.z * xv.y; acc[2][2] += wv.z * xv.z; acc[2][3] += wv.z * xv.w;
    acc[3][0] += wv.w * xv.x; acc[3][1] += wv.w * xv.y; acc[3][2] += wv.w * xv.z; acc[3][3] += wv.w * xv.w;
  }
  __hip_bfloat16* gxB = (__hip_bfloat16*)(ws + OFF_GXB);
  int n4g = n0 + n4;
  int jt  = n4g >> 5;
  int lhi = ((n4g >> 3) & 3) << 4;
  int sub = n4g & 7;
#pragma unroll
  for (int oo = 0; oo < 4; ++oo) {
    int o = o4 + oo;
    float gb = g_b[o];
    ushort4 pk = make_ushort4(f2bf(acc[oo][0] + gb), f2bf(acc[oo][1] + gb),
                              f2bf(acc[oo][2] + gb), f2bf(acc[oo][3] + gb));
    size_t idx = ((((size_t)b * 64 + jt) * 4 + (o >> 4)) * 64 + ((o & 15) | lhi)) * 8 + sub;
    *(ushort4*)(gxB + idx) = pk;
  }

  {
    int n = t & 63, qr = t >> 6;
    float ft = 0.f, fp = 0.f;
#pragma unroll 8
    for (int cc = 0; cc < 32; ++cc) {
      int c = qr * 32 + cc;
      float xv = xs[c][n];
      ft += xv * vtp[0][c];
      fp += xv * vtp[1][c];
    }
    fred[0][qr][n] = ft;
    fred[1][qr][n] = fp;
  }
  __syncthreads();
  if (t < 128) {
    int n = t & 63, isp = t >> 6;
    float f = fb[isp] + fred[isp][0][n] + fred[isp][1][n]
            + fred[isp][2][n] + fred[isp][3][n];
    ws[(isp ? OFF_FP : OFF_FT) + b * N_ + n0 + n] = f;
  }
}

// ---------------------------------------------------------------------------
// K2: fused attention, TLP formulation. Block = (b, 16-row tile), 4 waves;
// wave w owns j-quarter [w*512, w*512+512) = 16 windows, ALL 64 o (1x P).
// Per window: 1 broadcast u32 mask + 2 broadcast float4 f_p + 4 coalesced
// 1KB gxB B-frags -> softmax in A-frag layout -> 4 MFMA. No prefetch games:
// 16 waves/CU TLP hides latency. One barrier: 4-way j-merge via LDS.
// ---------------------------------------------------------------------------
__global__ __launch_bounds__(256, 4) void k_attn(const float* __restrict__ ws,
                                                 float* __restrict__ out) {
  __shared__ float mrg[4][64][16];   // 16 KB  per-wave D partials
  __shared__ float mrs[4][16];       // 256 B  per-wave rowsum partials

  int bx = blockIdx.x;
  int b = bx >> 7, rt = bx & 127;
  int rowbase = rt * 16;
  int t = threadIdx.x;
  int w = t >> 6, lane = t & 63;
  int col = lane & 15, agrp = lane >> 4;

  const float* f_t = ws + OFF_FT + b * N_;
  const unsigned* adjP = (const unsigned*)(ws + OFF_ADJP);
  const float4* fpv = (const float4*)(ws + OFF_FP + b * N_);
  const bf16x8* gx = (const bf16x8*)(ws + OFF_GXB)
                   + (size_t)b * 64 * 4 * 64 + lane;

  float fti = f_t[rowbase + col];

  f32x4 acc[4];
#pragma unroll
  for (int ot = 0; ot < 4; ++ot) acc[ot] = (f32x4){0.f, 0.f, 0.f, 0.f};
  float rsum = 0.f;

  for (int kw = 0; kw < 16; ++kw) {
    int jt = w * 16 + kw;
    unsigned m32 = adjP[(size_t)jt * 2048 + rowbase + col];
    float4 f0 = fpv[jt * 8 + agrp * 2];
    float4 f1 = fpv[jt * 8 + agrp * 2 + 1];
    unsigned mb = (m32 >> (agrp * 8)) & 0xffu;

    float s0 = fti + f0.x; s0 = fmaxf(s0, 0.2f * s0);
    float s1 = fti + f0.y; s1 = fmaxf(s1, 0.2f * s1);
    float s2 = fti + f0.z; s2 = fmaxf(s2, 0.2f * s2);
    float s3 = fti + f0.w; s3 = fmaxf(s3, 0.2f * s3);
    float s4 = fti + f1.x; s4 = fmaxf(s4, 0.2f * s4);
    float s5 = fti + f1.y; s5 = fmaxf(s5, 0.2f * s5);
    float s6 = fti + f1.z; s6 = fmaxf(s6, 0.2f * s6);
    float s7 = fti + f1.w; s7 = fmaxf(s7, 0.2f * s7);
    float p0 = (mb & 1u)   ? 0.f : exp2f(s0);
    float p1 = (mb & 2u)   ? 0.f : exp2f(s1);
    float p2 = (mb & 4u)   ? 0.f : exp2f(s2);
    float p3 = (mb & 8u)   ? 0.f : exp2f(s3);
    float p4 = (mb & 16u)  ? 0.f : exp2f(s4);
    float p5 = (mb & 32u)  ? 0.f : exp2f(s5);
    float p6 = (mb & 64u)  ? 0.f : exp2f(s6);
    float p7 = (mb & 128u) ? 0.f : exp2f(s7);
    rsum += ((p0 + p1) + (p2 + p3)) + ((p4 + p5) + (p6 + p7));

    bf16x8 af;
    af[0] = (short)f2bf(p0); af[1] = (short)f2bf(p1);
    af[2] = (short)f2bf(p2); af[3] = (short)f2bf(p3);
    af[4] = (short)f2bf(p4); af[5] = (short)f2bf(p5);
    af[6] = (short)f2bf(p6); af[7] = (short)f2bf(p7);

    const bf16x8* gp = gx + (size_t)jt * 4 * 64;
    acc[0] = __builtin_amdgcn_mfma_f32_16x16x32_bf16(af, gp[0],       acc[0], 0, 0, 0);
    acc[1] = __builtin_amdgcn_mfma_f32_16x16x32_bf16(af, gp[64],      acc[1], 0, 0, 0);
    acc[2] = __builtin_amdgcn_mfma_f32_16x16x32_bf16(af, gp[2 * 64],  acc[2], 0, 0, 0);
    acc[3] = __builtin_amdgcn_mfma_f32_16x16x32_bf16(af, gp[3 * 64],  acc[3], 0, 0, 0);
  }

  // wave-local rowsum: combine the 4 agrp k-subgroups of each row
  rsum += __shfl_xor(rsum, 16, 64);
  rsum += __shfl_xor(rsum, 32, 64);

  // publish wave partials
#pragma unroll
  for (int ot = 0; ot < 4; ++ot) *(f32x4*)&mrg[w][lane][ot * 4] = acc[ot];
  if (agrp == 0) mrs[w][col] = rsum;
  __syncthreads();

  // merge 4 j-quarters + normalize + store (all 256 threads; 4 outputs each)
  int o = t & 63, rb4 = (t >> 6) * 4;
  float res[4];
#pragma unroll
  for (int rr = 0; rr < 4; ++rr) {
    int row = rb4 + rr;
    int li = (row >> 2) * 16 + (o & 15);
    int vi = (o >> 4) * 4 + (row & 3);
    float v = mrg[0][li][vi] + mrg[1][li][vi] + mrg[2][li][vi] + mrg[3][li][vi];
    float rs = mrs[0][row] + mrs[1][row] + mrs[2][row] + mrs[3][row];
    res[rr] = v / rs;
  }
  float* op = out + ((size_t)b * IC_ + o) * N_ + rowbase + rb4;
  *(float4*)op = make_float4(res[0], res[1], res[2], res[3]);
}

// ---------------------------------------------------------------------------
extern "C" void kernel_launch(void* const* d_in, const int* in_sizes, int n_in,
                              void* d_out, int out_size, void* d_ws, size_t ws_size,
                              hipStream_t stream) {
  const float* x       = (const float*)d_in[0];
  const int*   adj     = (const int*)  d_in[1];
  const float* g_w     = (const float*)d_in[2];
  const float* g_b     = (const float*)d_in[3];
  const float* theta_w = (const float*)d_in[4];
  const float* theta_b = (const float*)d_in[5];
  const float* phi_w   = (const float*)d_in[6];
  const float* phi_b   = (const float*)d_in[7];
  const float* cp_w    = (const float*)d_in[8];
  float* out = (float*)d_out;
  float* ws  = (float*)d_ws;

  k_pack<<<N_, 256, 0, stream>>>(adj, ws);
  k_gx<<<B_ * (N_ / 64), 256, 0, stream>>>(x, g_w, g_b, theta_w, theta_b,
                                           phi_w, phi_b, cp_w, ws);
  k_attn<<<B_ * (N_ / 16), 256, 0, stream>>>(ws, out);
}